// Round 1
// baseline (133.514 us; speedup 1.0000x reference)
//
#include <hip/hip_runtime.h>

#define NX 192
#define TILE 16
#define ZCHUNK 32
#define LDSW 18   // TILE + 2 halo

// One block: 16x16 threads, owns a 16x16 (x,y) tile, slides over ZCHUNK z-slices.
// Per slice: stage 18x18 halo tile of pred/targ in LDS, compute the five 3x3
// 2D window sums per thread, keep a 3-slice register ring to form 3x3x3 sums.
__global__ __launch_bounds__(256) void lncc_main(const float* __restrict__ pred,
                                                 const float* __restrict__ targ,
                                                 double* __restrict__ acc) {
    __shared__ float sI[LDSW * LDSW];
    __shared__ float sJ[LDSW * LDSW];
    __shared__ float wred[4];

    const int tx = threadIdx.x;            // 0..15
    const int ty = threadIdx.y;            // 0..15
    const int tid = ty * 16 + tx;
    const int x0 = blockIdx.x * TILE;
    const int y0 = blockIdx.y * TILE;
    const int z0 = blockIdx.z * ZCHUNK;

    // register ring: 2D window sums for slices z-2 (p*) and z-1 (c*)
    float pI = 0.f, pJ = 0.f, pII = 0.f, pJJ = 0.f, pIJ = 0.f;
    float cI = 0.f, cJ = 0.f, cII = 0.f, cJJ = 0.f, cIJ = 0.f;
    float nccSum = 0.f;

    for (int s = 0; s < ZCHUNK + 2; ++s) {
        const int z = z0 - 1 + s;
        // ---- stage slice z into LDS (zero pad out-of-volume) ----
        if (z >= 0 && z < NX) {
            const float* pz = pred + (size_t)z * NX * NX;
            const float* tz = targ + (size_t)z * NX * NX;
            for (int i = tid; i < LDSW * LDSW; i += 256) {
                const int ly = i / LDSW;
                const int lx = i - ly * LDSW;
                const int gy = y0 - 1 + ly;
                const int gx = x0 - 1 + lx;
                float a = 0.f, b = 0.f;
                if (gx >= 0 && gx < NX && gy >= 0 && gy < NX) {
                    const int off = gy * NX + gx;
                    a = pz[off];
                    b = tz[off];
                }
                sI[i] = a;
                sJ[i] = b;
            }
        } else {
            for (int i = tid; i < LDSW * LDSW; i += 256) {
                sI[i] = 0.f;
                sJ[i] = 0.f;
            }
        }
        __syncthreads();

        // ---- 3x3 2D window sums for this slice ----
        float nI = 0.f, nJ = 0.f, nII = 0.f, nJJ = 0.f, nIJ = 0.f;
#pragma unroll
        for (int dy = 0; dy < 3; ++dy) {
#pragma unroll
            for (int dx = 0; dx < 3; ++dx) {
                const float a = sI[(ty + dy) * LDSW + tx + dx];
                const float b = sJ[(ty + dy) * LDSW + tx + dx];
                nI += a;
                nJ += b;
                nII = fmaf(a, a, nII);
                nJJ = fmaf(b, b, nJJ);
                nIJ = fmaf(a, b, nIJ);
            }
        }

        // ---- emit output for slice z-1 once we hold z-2, z-1, z ----
        if (s >= 2) {
            const float Is  = pI  + cI  + nI;
            const float Js  = pJ  + cJ  + nJ;
            const float IIs = pII + cII + nII;
            const float JJs = pJJ + cJJ + nJJ;
            const float IJs = pIJ + cIJ + nIJ;
            const float inv = 1.f / 27.f;
            const float uI = Is * inv;
            const float uJ = Js * inv;
            const float cross = IJs - uJ * Is;
            const float Ivar  = IIs - uI * Is;
            const float Jvar  = JJs - uJ * Js;
            nccSum += (cross * cross) / (Ivar * Jvar + 1e-5f);
        }
        pI = cI; pJ = cJ; pII = cII; pJJ = cJJ; pIJ = cIJ;
        cI = nI; cJ = nJ; cII = nII; cJJ = nJJ; cIJ = nIJ;
        __syncthreads();   // protect LDS before next slice load
    }

    // ---- block reduction: wave shuffle -> LDS -> one f64 atomic ----
    float v = nccSum;
#pragma unroll
    for (int off = 32; off > 0; off >>= 1) v += __shfl_down(v, off);
    const int lane = tid & 63;
    const int wid = tid >> 6;
    if (lane == 0) wred[wid] = v;
    __syncthreads();
    if (tid == 0) {
        const double t = (double)wred[0] + (double)wred[1] +
                         (double)wred[2] + (double)wred[3];
        atomicAdd(acc, t);
    }
}

__global__ void lncc_final(const double* __restrict__ acc, float* __restrict__ out) {
    const double n = (double)NX * NX * NX;
    out[0] = (float)(-acc[0] / n);
}

extern "C" void kernel_launch(void* const* d_in, const int* in_sizes, int n_in,
                              void* d_out, int out_size, void* d_ws, size_t ws_size,
                              hipStream_t stream) {
    const float* pred = (const float*)d_in[0];
    const float* targ = (const float*)d_in[1];
    double* acc = (double*)d_ws;
    float* out = (float*)d_out;

    hipMemsetAsync(acc, 0, sizeof(double), stream);

    dim3 grid(NX / TILE, NX / TILE, NX / ZCHUNK);   // 12 x 12 x 6
    dim3 block(TILE, TILE);                          // 256 threads
    lncc_main<<<grid, block, 0, stream>>>(pred, targ, acc);
    lncc_final<<<1, 1, 0, stream>>>(acc, out);
}

// Round 2
// 129.124 us; speedup vs baseline: 1.0340x; 1.0340x over previous
//
#include <hip/hip_runtime.h>

#define NX 192
#define TILE 16
#define ZC 8                       // z-slices emitted per block
#define LDSW 18                    // TILE + 2 halo
#define NEL (LDSW * LDSW)          // 324
#define NBLK ((NX/TILE)*(NX/TILE)*(NX/ZC))   // 12*12*24 = 3456

// Block: 16x16 threads own a 16x16 (x,y) tile, slide over ZC z-slices.
// Double-buffered LDS slice (float2 {pred,targ}) -> ONE barrier per slice.
// Global loads for slice s+1 are issued right after the barrier of slice s,
// so their latency overlaps the 3x3 compute and other resident waves.
__global__ __launch_bounds__(256) void lncc_main(const float* __restrict__ pred,
                                                 const float* __restrict__ targ,
                                                 double* __restrict__ partial) {
    __shared__ float2 sAB[2][NEL];
    __shared__ float wred[4];

    const int tx = threadIdx.x;        // 0..15
    const int ty = threadIdx.y;        // 0..15
    const int tid = ty * 16 + tx;
    const int x0 = blockIdx.x * TILE;
    const int y0 = blockIdx.y * TILE;
    const int z0 = blockIdx.z * ZC;

    // staging coords: element i -> (ly,lx) in the 18x18 halo tile
    const int i0 = tid;
    const int i1 = tid + 256;
    const int ly0 = i0 / LDSW, lx0 = i0 - ly0 * LDSW;
    const int gy0 = y0 - 1 + ly0, gx0 = x0 - 1 + lx0;
    const bool ok0 = ((unsigned)gx0 < NX) && ((unsigned)gy0 < NX);
    const int off0 = gy0 * NX + gx0;
    const bool has1 = (i1 < NEL);
    const int ly1 = i1 / LDSW, lx1 = i1 - ly1 * LDSW;
    const int gy1 = y0 - 1 + ly1, gx1 = x0 - 1 + lx1;
    const bool ok1 = has1 && ((unsigned)gx1 < NX) && ((unsigned)gy1 < NX);
    const int off1 = gy1 * NX + gx1;

    // prefetch registers for the slice about to be written to LDS
    float a0 = 0.f, b0 = 0.f, a1 = 0.f, b1 = 0.f;
    {   // slice z0-1 (z0 <= 184 so z < NX always; only z >= 0 can fail)
        const int z = z0 - 1;
        if (z >= 0) {
            const size_t zb = (size_t)z * NX * NX;
            if (ok0) { a0 = pred[zb + off0]; b0 = targ[zb + off0]; }
            if (ok1) { a1 = pred[zb + off1]; b1 = targ[zb + off1]; }
        }
    }

    // z-ring of 2D window sums: p* = slice z-2, c* = slice z-1
    float pI = 0.f, pJ = 0.f, pII = 0.f, pJJ = 0.f, pIJ = 0.f;
    float cI = 0.f, cJ = 0.f, cII = 0.f, cJJ = 0.f, cIJ = 0.f;
    float nccSum = 0.f;

    for (int s = 0; s < ZC + 2; ++s) {
        float2* buf = sAB[s & 1];
        buf[i0] = make_float2(a0, b0);
        if (has1) buf[i1] = make_float2(a1, b1);
        __syncthreads();   // single barrier: next write to THIS buffer is 2 iters away

        // issue prefetch of slice z0+s (consumed at next iteration's LDS write)
        {
            const int z = z0 + s;       // >= 0 always
            a0 = b0 = a1 = b1 = 0.f;
            if (z < NX) {
                const size_t zb = (size_t)z * NX * NX;
                if (ok0) { a0 = pred[zb + off0]; b0 = targ[zb + off0]; }
                if (ok1) { a1 = pred[zb + off1]; b1 = targ[zb + off1]; }
            }
        }

        // 3x3 2D window sums from LDS (ds_read_b64, conflict-free)
        float nI = 0.f, nJ = 0.f, nII = 0.f, nJJ = 0.f, nIJ = 0.f;
#pragma unroll
        for (int dy = 0; dy < 3; ++dy) {
#pragma unroll
            for (int dx = 0; dx < 3; ++dx) {
                const float2 ab = buf[(ty + dy) * LDSW + tx + dx];
                nI += ab.x;
                nJ += ab.y;
                nII = fmaf(ab.x, ab.x, nII);
                nJJ = fmaf(ab.y, ab.y, nJJ);
                nIJ = fmaf(ab.x, ab.y, nIJ);
            }
        }

        if (s >= 2) {
            const float Is  = pI  + cI  + nI;
            const float Js  = pJ  + cJ  + nJ;
            const float IIs = pII + cII + nII;
            const float JJs = pJJ + cJJ + nJJ;
            const float IJs = pIJ + cIJ + nIJ;
            const float inv = 1.f / 27.f;
            const float uI = Is * inv;
            const float uJ = Js * inv;
            const float cross = IJs - uJ * Is;
            const float Ivar  = IIs - uI * Is;
            const float Jvar  = JJs - uJ * Js;
            nccSum += (cross * cross) / (Ivar * Jvar + 1e-5f);
        }
        pI = cI; pJ = cJ; pII = cII; pJJ = cJJ; pIJ = cIJ;
        cI = nI; cJ = nJ; cII = nII; cJJ = nJJ; cIJ = nIJ;
    }

    // block reduction -> one double partial per block (no atomics, no memset)
    float v = nccSum;
#pragma unroll
    for (int off = 32; off > 0; off >>= 1) v += __shfl_down(v, off);
    if ((tid & 63) == 0) wred[tid >> 6] = v;
    __syncthreads();
    if (tid == 0) {
        const int bid = (blockIdx.z * gridDim.y + blockIdx.y) * gridDim.x + blockIdx.x;
        partial[bid] = (double)wred[0] + (double)wred[1] +
                       (double)wred[2] + (double)wred[3];
    }
}

__global__ __launch_bounds__(256) void lncc_reduce(const double* __restrict__ partial,
                                                   float* __restrict__ out) {
    __shared__ double dred[4];
    double sum = 0.0;
    for (int i = threadIdx.x; i < NBLK; i += 256) sum += partial[i];
#pragma unroll
    for (int off = 32; off > 0; off >>= 1) sum += __shfl_down(sum, off);
    if ((threadIdx.x & 63) == 0) dred[threadIdx.x >> 6] = sum;
    __syncthreads();
    if (threadIdx.x == 0) {
        const double n = (double)NX * NX * NX;
        out[0] = (float)(-(dred[0] + dred[1] + dred[2] + dred[3]) / n);
    }
}

extern "C" void kernel_launch(void* const* d_in, const int* in_sizes, int n_in,
                              void* d_out, int out_size, void* d_ws, size_t ws_size,
                              hipStream_t stream) {
    const float* pred = (const float*)d_in[0];
    const float* targ = (const float*)d_in[1];
    double* partial = (double*)d_ws;      // NBLK doubles, fully overwritten each call
    float* out = (float*)d_out;

    dim3 grid(NX / TILE, NX / TILE, NX / ZC);   // 12 x 12 x 24 = 3456 blocks
    dim3 block(TILE, TILE);                      // 256 threads
    lncc_main<<<grid, block, 0, stream>>>(pred, targ, partial);
    lncc_reduce<<<1, 256, 0, stream>>>(partial, out);
}